// Round 1
// 724.097 us; speedup vs baseline: 1.0042x; 1.0042x over previous
//
#include <hip/hip_runtime.h>

// FullTensorProduct: N=4096 rows, MUL=64.
// in1,in2: (N, 256) fp32; out: (N, 45056) fp32.
// Row layout: [c000: 4096][c110: 4096][c011: 12288][c101: 12288][c111: 12288]
// Write-BW-bound: 738 MB out vs 8 MB in. Roofline ~118 us at 6.25 TB/s.
//
// Structure: one thread owns one (u, v-quad). 4 blocks per row, 256 thr each:
//   block j covers u in [16j, 16j+16); thread t: u = 16j + (t>>4), v = 4*(t&15).
// All operands register-resident via 6 vector LDS reads; 44 output floats
// computed straight-line; 11 float4 stores, compile-time offsets, no div/mod.

#define ROW_IN   256
#define ROW_OUT  45056

__global__ __launch_bounds__(256) void ftp_kernel(
    const float* __restrict__ in1,
    const float* __restrict__ in2,
    float* __restrict__ out)
{
    __shared__ float sa[ROW_IN];   // a0[0:64], a1 flat [64:256] (u*3+i)
    __shared__ float sb[ROW_IN];   // b0[0:64], b1 flat [64:256] (v*3+j)

    const int bid = blockIdx.x;
    const int row = bid >> 2;      // 4 blocks per row
    const int jb  = bid & 3;       // which u-quarter
    const int t   = threadIdx.x;

    sa[t] = in1[(size_t)row * ROW_IN + t];
    sb[t] = in2[(size_t)row * ROW_IN + t];
    __syncthreads();

    const int u  = (jb << 4) + (t >> 4);   // u in [0,64)
    const int vq = t & 15;                 // v-quad index
    const int v  = vq << 2;                // v in [0,64) step 4

    // a-operands (broadcast across the 16 threads sharing u)
    const float a0u = sa[u];
    const float ax  = sa[64 + u * 3 + 0];
    const float ay  = sa[64 + u * 3 + 1];
    const float az  = sa[64 + u * 3 + 2];

    // b-operands, vector loads. b1 block: 12 floats at byte offset 256+48*vq
    // (48 = 16*3 -> always 16B aligned).
    const float4 b0v = *(const float4*)(sb + v);
    const float4 q0  = *(const float4*)(sb + 64 + v * 3);
    const float4 q1  = *(const float4*)(sb + 64 + v * 3 + 4);
    const float4 q2  = *(const float4*)(sb + 64 + v * 3 + 8);

    const float b1x0 = q0.x, b1y0 = q0.y, b1z0 = q0.z;
    const float b1x1 = q0.w, b1y1 = q1.x, b1z1 = q1.y;
    const float b1x2 = q1.z, b1y2 = q1.w, b1z2 = q2.x;
    const float b1x3 = q2.y, b1y3 = q2.z, b1z3 = q2.w;

    constexpr float INV_SQRT3 = 0.57735026918962576f;
    constexpr float INV_SQRT2 = 0.70710678118654752f;

    float4* __restrict__ outr = (float4*)(out + (size_t)row * ROW_OUT);
    // region bases in float4 units:
    // c000 @ 0, c110 @ 1024, c011 @ 2048, c101 @ 5120, c111 @ 8192

    const int f00   = u * 16 + vq;        // = 256*jb + t  (coalesced)
    const int base3 = u * 48 + vq * 3;    // 3-component regions

    // ---- c000: a0[u] * b0[v..v+3] ----
    {
        float4 r;
        r.x = a0u * b0v.x;
        r.y = a0u * b0v.y;
        r.z = a0u * b0v.z;
        r.w = a0u * b0v.w;
        outr[f00] = r;
    }

    // ---- c110: dot3(a1[u], b1[v]) / sqrt3 ----
    {
        float4 r;
        r.x = (ax * b1x0 + ay * b1y0 + az * b1z0) * INV_SQRT3;
        r.y = (ax * b1x1 + ay * b1y1 + az * b1z1) * INV_SQRT3;
        r.z = (ax * b1x2 + ay * b1y2 + az * b1z2) * INV_SQRT3;
        r.w = (ax * b1x3 + ay * b1y3 + az * b1z3) * INV_SQRT3;
        outr[1024 + f00] = r;
    }

    // ---- c011: a0[u] * b1[v, j], flat (v,j) order ----
    {
        float4 r0, r1, r2;
        r0.x = a0u * b1x0; r0.y = a0u * b1y0; r0.z = a0u * b1z0; r0.w = a0u * b1x1;
        r1.x = a0u * b1y1; r1.y = a0u * b1z1; r1.z = a0u * b1x2; r1.w = a0u * b1y2;
        r2.x = a0u * b1z2; r2.y = a0u * b1x3; r2.z = a0u * b1y3; r2.w = a0u * b1z3;
        outr[2048 + base3 + 0] = r0;
        outr[2048 + base3 + 1] = r1;
        outr[2048 + base3 + 2] = r2;
    }

    // ---- c101: a1[u, i] * b0[v], flat (v,i) order ----
    {
        float4 r0, r1, r2;
        r0.x = ax * b0v.x; r0.y = ay * b0v.x; r0.z = az * b0v.x; r0.w = ax * b0v.y;
        r1.x = ay * b0v.y; r1.y = az * b0v.y; r1.z = ax * b0v.z; r1.w = ay * b0v.z;
        r2.x = az * b0v.z; r2.y = ax * b0v.w; r2.z = ay * b0v.w; r2.w = az * b0v.w;
        outr[5120 + base3 + 0] = r0;
        outr[5120 + base3 + 1] = r1;
        outr[5120 + base3 + 2] = r2;
    }

    // ---- c111: cross(a1[u], b1[v]) / sqrt2, flat (v,k) order ----
    {
        const float c0x = (ay * b1z0 - az * b1y0) * INV_SQRT2;
        const float c0y = (az * b1x0 - ax * b1z0) * INV_SQRT2;
        const float c0z = (ax * b1y0 - ay * b1x0) * INV_SQRT2;
        const float c1x = (ay * b1z1 - az * b1y1) * INV_SQRT2;
        const float c1y = (az * b1x1 - ax * b1z1) * INV_SQRT2;
        const float c1z = (ax * b1y1 - ay * b1x1) * INV_SQRT2;
        const float c2x = (ay * b1z2 - az * b1y2) * INV_SQRT2;
        const float c2y = (az * b1x2 - ax * b1z2) * INV_SQRT2;
        const float c2z = (ax * b1y2 - ay * b1x2) * INV_SQRT2;
        const float c3x = (ay * b1z3 - az * b1y3) * INV_SQRT2;
        const float c3y = (az * b1x3 - ax * b1z3) * INV_SQRT2;
        const float c3z = (ax * b1y3 - ay * b1x3) * INV_SQRT2;
        float4 r0, r1, r2;
        r0.x = c0x; r0.y = c0y; r0.z = c0z; r0.w = c1x;
        r1.x = c1y; r1.y = c1z; r1.z = c2x; r1.w = c2y;
        r2.x = c2z; r2.y = c3x; r2.z = c3y; r2.w = c3z;
        outr[8192 + base3 + 0] = r0;
        outr[8192 + base3 + 1] = r1;
        outr[8192 + base3 + 2] = r2;
    }
}

extern "C" void kernel_launch(void* const* d_in, const int* in_sizes, int n_in,
                              void* d_out, int out_size, void* d_ws, size_t ws_size,
                              hipStream_t stream) {
    const float* in1 = (const float*)d_in[0];
    const float* in2 = (const float*)d_in[1];
    float* out = (float*)d_out;
    const int N = in_sizes[0] / ROW_IN;   // 4096
    ftp_kernel<<<(N * 4), 256, 0, stream>>>(in1, in2, out);
}